// Round 4
// baseline (2172.150 us; speedup 1.0000x reference)
//
#include <hip/hip_runtime.h>

typedef unsigned short u16;
typedef unsigned int u32;
typedef __attribute__((ext_vector_type(8))) short bf16x8;
typedef __attribute__((ext_vector_type(4))) float f32x4;

#define TR 261888           // total anchor rows per batch image
#define LOGITS_OFF 0
#define PROBS_OFF  1047552  // 2*TR*2
#define DELTAS_OFF 2095104  // 2*(2*TR*2)

#define W3P_ELEMS (72 * 512 * 32)
#define W18P_ELEMS (32 * 512)
#define FLAG_OFF_BYTES ((W3P_ELEMS + W18P_ELEMS) * 2)

#define ABSTRIDE 7920        // u16 elems per A halo buffer (max: 198 px * 40)

__device__ __forceinline__ float b2f(u16 u) {
    union { u32 i; float f; } v; v.i = ((u32)u) << 16; return v.f;
}
__device__ __forceinline__ u16 f2b(float f) {
    union { float f; u32 i; } v; v.f = f;
    u32 x = v.i;
    return (u16)((x + 0x7fffu + ((x >> 16) & 1u)) >> 16);
}
__device__ __forceinline__ float bitsf(u32 b) {
    union { u32 i; float f; } v; v.i = b; return v.f;
}
__device__ __forceinline__ float ldmix(const void* p, int i, bool isb16) {
    return isb16 ? b2f(((const u16*)p)[i]) : ((const float*)p)[i];
}

// Sh layout: 64 px x 512 ch, stride 512, XOR swizzle (8-u16 granularity).
__device__ __forceinline__ int sh_idx(int px, int c) {
    return px * 512 + (c ^ ((px & 3) * 8));
}

// ---------------------------------------------------------------------------
__global__ void detect_kernel(const u16* __restrict__ f0, int* __restrict__ flag) {
    int lane = threadIdx.x;          // 64 threads
    u16 v = f0[lane * 2];            // even u16 index
    int e = (v >> 7) & 0xFF;
    bool plausible = (e >= 90) && (e <= 140);
    unsigned long long m = __ballot(plausible);
    if (lane == 0) *flag = (__popcll(m) >= 48) ? 1 : 0;   // 1 = bf16, 0 = f32
}

// ---------------------------------------------------------------------------
// Repack: w_shared [2304,512] -> W3p[72][512][32] bf16 (k-contig per n)
//         w_cls[512,6] + w_delta[512,12] -> W18p[32][512] bf16 (rows 18..31=0)
// ---------------------------------------------------------------------------
__global__ void repack_kernel(const void* __restrict__ w3,
                              const void* __restrict__ wcls,
                              const void* __restrict__ wdelta,
                              u16* __restrict__ W3p, u16* __restrict__ W18p,
                              const int* __restrict__ flag) {
    const bool isb16 = (*flag != 0);
    int tid = blockIdx.x * 256 + threadIdx.x;
    if (tid < W3P_ELEMS) {
        int k = tid & 31;
        int n = (tid >> 5) & 511;
        int c = tid >> 14;
        int K = c * 32 + k;
        W3p[tid] = f2b(ldmix(w3, K * 512 + n, isb16));
    } else if (tid < W3P_ELEMS + W18P_ELEMS) {
        int t = tid - W3P_ELEMS;
        int k = t & 511;
        int j = t >> 9;
        float v = 0.f;
        if (j < 6)       v = ldmix(wcls, k * 6 + j, isb16);
        else if (j < 18) v = ldmix(wdelta, k * 12 + (j - 6), isb16);
        W18p[t] = f2b(v);
    }
}

// ---------------------------------------------------------------------------
// Fused RPN head. One block = 64 consecutive row-major pixels (strip of
// R rows x C cols). K-loop: 8 ch-chunks; per chunk stage halo'd pixel tile
// ((R+2)x(C+2) x 32ch) to LDS once, run all 9 taps from LDS.
// Barriers: ~10/block. Double-buffered A via register prefetch.
// ---------------------------------------------------------------------------
__global__ __launch_bounds__(256, 2) void rpn_main(
    const void* __restrict__ f0, const void* __restrict__ f1,
    const void* __restrict__ f2, const void* __restrict__ f3,
    const void* __restrict__ f4,
    const void* __restrict__ bsh, const void* __restrict__ bcls,
    const void* __restrict__ bdelta,
    const u16* __restrict__ W3p, const u16* __restrict__ W18p,
    void* __restrict__ out, const int* __restrict__ flag)
{
    __shared__ u16 SMEM[32768];   // 64 KiB: A dbuf [0,15840) in K-loop; Sh after

    const bool isb16 = (*flag != 0);

    const int tid  = threadIdx.x;
    const int wv   = tid >> 6;
    const int lane = tid & 63;
    const int quad = lane >> 4;
    const int l16  = lane & 15;

    // level decode (uniform per block)
    const int bid = blockIdx.x;
    const int lvl = (bid >= 2048) + (bid >= 2560) + (bid >= 2688) + (bid >= 2720);
    const int tileBase = (lvl == 0) ? 0 : (lvl == 1) ? 2048 : (lvl == 2) ? 2560
                        : (lvl == 3) ? 2688 : 2720;
    const int logS   = 8 - lvl;
    const int S      = 1 << logS;
    const int rowOff = (lvl == 0) ? 0 : (lvl == 1) ? 196608 : (lvl == 2) ? 245760
                      : (lvl == 3) ? 258048 : 261120;
    const void* feat = (lvl == 0) ? f0 : (lvl == 1) ? f1 : (lvl == 2) ? f2
                      : (lvl == 3) ? f3 : f4;
    const int tile = bid - tileBase;

    const int logC = (logS > 6) ? 6 : logS;    // strip: R rows x C cols
    const int C    = 1 << logC;
    const int R    = 1 << (6 - logC);
    const int hden = C + 2;                    // halo row width
    const int HP   = (R + 2) * hden;           // halo pixel count
    const int units = HP * 4;                  // staging units (8ch each)

    const int P0  = tile * 64;
    const int b   = P0 >> (2 * logS);
    const int pin = P0 & ((1 << (2 * logS)) - 1);
    const int h0  = pin >> logS;
    const int w0  = pin & (S - 1);

    // ---- staging prefetch (raw bits; f32 path uses both uint4s) ----
    uint4 pf[4][2];
    auto loadRegs = [&](int cc) {
#pragma unroll
        for (int it = 0; it < 4; ++it) {
            const int u = tid + it * 256;
            pf[it][0] = make_uint4(0u, 0u, 0u, 0u);
            pf[it][1] = make_uint4(0u, 0u, 0u, 0u);
            if (u < units) {
                const int ch8 = (u & 3) * 8;
                const int hpx = u >> 2;
                const int hr = hpx / hden;
                const int hc = hpx - hr * hden;
                const int h = h0 + hr - 1;
                const int w = w0 + hc - 1;
                if (h >= 0 && h < S && w >= 0 && w < S) {
                    const size_t g = ((size_t)((b * S + h) * S + w)) * 256 + cc * 32 + ch8;
                    if (isb16) {
                        pf[it][0] = *(const uint4*)((const u16*)feat + g);
                    } else {
                        const float* fp = (const float*)feat + g;
                        pf[it][0] = *(const uint4*)fp;
                        pf[it][1] = *(const uint4*)(fp + 4);
                    }
                }
            }
        }
    };
    auto storeLDS = [&](int bufbase) {
#pragma unroll
        for (int it = 0; it < 4; ++it) {
            const int u = tid + it * 256;
            if (u < units) {
                const int ch8 = (u & 3) * 8;
                const int hpx = u >> 2;
                uint4 v;
                if (isb16) {
                    v = pf[it][0];
                } else {
                    const uint4 a = pf[it][0], c = pf[it][1];
                    v.x = (u32)f2b(bitsf(a.x)) | ((u32)f2b(bitsf(a.y)) << 16);
                    v.y = (u32)f2b(bitsf(a.z)) | ((u32)f2b(bitsf(a.w)) << 16);
                    v.z = (u32)f2b(bitsf(c.x)) | ((u32)f2b(bitsf(c.y)) << 16);
                    v.w = (u32)f2b(bitsf(c.z)) | ((u32)f2b(bitsf(c.w)) << 16);
                }
                *(uint4*)&SMEM[bufbase + hpx * 40 + ch8] = v;
            }
        }
    };

    const f32x4 zf = {0.f, 0.f, 0.f, 0.f};
    f32x4 acc[4][8];
#pragma unroll
    for (int mt = 0; mt < 4; ++mt)
#pragma unroll
        for (int nt = 0; nt < 8; ++nt) acc[mt][nt] = zf;

    // ---------------- K loop: 8 ch-chunks x 9 taps ----------------
    loadRegs(0);
    for (int cc = 0; cc < 8; ++cc) {
        const int bufbase = (cc & 1) * ABSTRIDE;
        storeLDS(bufbase);
        if (cc < 7) loadRegs(cc + 1);   // async; waited next iter (hidden)
        __syncthreads();

#pragma unroll
        for (int tap = 0; tap < 9; ++tap) {
            const int dh = tap / 3 - 1, dw = tap % 3 - 1;
            const int kc = tap * 8 + cc;
            bf16x8 bfr[8];
#pragma unroll
            for (int nt = 0; nt < 8; ++nt) {
                size_t off = ((size_t)kc * 512 +
                              (size_t)(wv * 128 + nt * 16 + l16)) * 32 + quad * 8;
                bfr[nt] = *(const bf16x8*)&W3p[off];
            }
#pragma unroll
            for (int mt = 0; mt < 4; ++mt) {
                const int r0 = (mt * 16) >> logC;          // uniform per mt
                const int c0 = (mt * 16 & (C - 1)) + l16;
                const int idx = bufbase +
                    ((r0 + 1 + dh) * hden + (c0 + 1 + dw)) * 40 + quad * 8;
                bf16x8 af = *(const bf16x8*)&SMEM[idx];
#pragma unroll
                for (int nt = 0; nt < 8; ++nt)
                    acc[mt][nt] = __builtin_amdgcn_mfma_f32_16x16x32_bf16(
                        af, bfr[nt], acc[mt][nt], 0, 0, 0);
            }
        }
    }

    __syncthreads();   // all waves done with A buffers before Sh overwrites

    // ---------------- epilogue 1: bias + relu -> Sh (bf16, swizzled) --------
#pragma unroll
    for (int nt = 0; nt < 8; ++nt) {
        const int n = wv * 128 + nt * 16 + l16;
        const float bn = ldmix(bsh, n, isb16);
#pragma unroll
        for (int mt = 0; mt < 4; ++mt) {
#pragma unroll
            for (int r = 0; r < 4; ++r) {
                const int px = mt * 16 + quad * 4 + r;
                float vv = acc[mt][nt][r] + bn;
                vv = vv > 0.f ? vv : 0.f;
                SMEM[sh_idx(px, n)] = f2b(vv);
            }
        }
    }
    __syncthreads();

    // ---------------- GEMM2: out18 = W18 (A, m=j) x Sh^T (B, n=px) ----------
    f32x4 a2[2];
    a2[0] = zf; a2[1] = zf;
#pragma unroll
    for (int jt = 0; jt < 2; ++jt) {
#pragma unroll
        for (int ks = 0; ks < 16; ++ks) {
            bf16x8 wa = *(const bf16x8*)&W18p[(jt * 16 + l16) * 512 + ks * 32 + quad * 8];
            bf16x8 sb = *(const bf16x8*)&SMEM[sh_idx(wv * 16 + l16, ks * 32 + quad * 8)];
            a2[jt] = __builtin_amdgcn_mfma_f32_16x16x32_bf16(wa, sb, a2[jt], 0, 0, 0);
        }
    }

    // ---------------- outputs (paired float2 / u32 stores) ----------------
    const int Pimg = pin + wv * 16 + l16;          // this lane's pixel
    const size_t rowBase = (size_t)b * TR + rowOff + (size_t)Pimg * 3;
    const size_t rb2 = rowBase * 2;                // logits/probs elem base
    const size_t rb4 = rowBase * 4;                // deltas elem base
    u16*   o16 = (u16*)out;
    float* o32 = (float*)out;
    auto st2 = [&](size_t elem, float v0, float v1) {   // elem always even
        if (isb16) {
            u32 p = (u32)f2b(v0) | ((u32)f2b(v1) << 16);
            *(u32*)&o16[elem] = p;
        } else {
            *(float2*)&o32[elem] = make_float2(v0, v1);
        }
    };
    auto smax = [&](float L0, float L1, float& P0, float& P1) {
        const float m = fmaxf(L0, L1);
        const float e0 = __expf(L0 - m), e1 = __expf(L1 - m);
        const float inv = 1.0f / (e0 + e1);
        P0 = e0 * inv; P1 = e1 * inv;
    };

    if (quad == 0) {
        // j0..3 -> logits rows 0,1 ; j16,17 -> deltas 10,11
        float L0 = a2[0][0] + ldmix(bcls, 0, isb16);
        float L1 = a2[0][1] + ldmix(bcls, 1, isb16);
        float L2 = a2[0][2] + ldmix(bcls, 2, isb16);
        float L3 = a2[0][3] + ldmix(bcls, 3, isb16);
        st2(LOGITS_OFF + rb2 + 0, L0, L1);
        st2(LOGITS_OFF + rb2 + 2, L2, L3);
        float P0, P1, P2, P3;
        smax(L0, L1, P0, P1); smax(L2, L3, P2, P3);
        st2(PROBS_OFF + rb2 + 0, P0, P1);
        st2(PROBS_OFF + rb2 + 2, P2, P3);
        float d10 = a2[1][0] + ldmix(bdelta, 10, isb16);
        float d11 = a2[1][1] + ldmix(bdelta, 11, isb16);
        st2(DELTAS_OFF + rb4 + 10, d10, d11);
    } else if (quad == 1) {
        // j4,5 -> logits row 2 ; j6,7 -> deltas 0,1
        float L4 = a2[0][0] + ldmix(bcls, 4, isb16);
        float L5 = a2[0][1] + ldmix(bcls, 5, isb16);
        st2(LOGITS_OFF + rb2 + 4, L4, L5);
        float P4, P5; smax(L4, L5, P4, P5);
        st2(PROBS_OFF + rb2 + 4, P4, P5);
        float d0 = a2[0][2] + ldmix(bdelta, 0, isb16);
        float d1 = a2[0][3] + ldmix(bdelta, 1, isb16);
        st2(DELTAS_OFF + rb4 + 0, d0, d1);
    } else if (quad == 2) {
        // j8..11 -> deltas 2..5
        float d2 = a2[0][0] + ldmix(bdelta, 2, isb16);
        float d3 = a2[0][1] + ldmix(bdelta, 3, isb16);
        float d4 = a2[0][2] + ldmix(bdelta, 4, isb16);
        float d5 = a2[0][3] + ldmix(bdelta, 5, isb16);
        st2(DELTAS_OFF + rb4 + 2, d2, d3);
        st2(DELTAS_OFF + rb4 + 4, d4, d5);
    } else {
        // j12..15 -> deltas 6..9
        float d6 = a2[0][0] + ldmix(bdelta, 6, isb16);
        float d7 = a2[0][1] + ldmix(bdelta, 7, isb16);
        float d8 = a2[0][2] + ldmix(bdelta, 8, isb16);
        float d9 = a2[0][3] + ldmix(bdelta, 9, isb16);
        st2(DELTAS_OFF + rb4 + 6, d6, d7);
        st2(DELTAS_OFF + rb4 + 8, d8, d9);
    }
}

// ---------------------------------------------------------------------------
extern "C" void kernel_launch(void* const* d_in, const int* in_sizes, int n_in,
                              void* d_out, int out_size, void* d_ws, size_t ws_size,
                              hipStream_t stream) {
    const void* f0     = d_in[0];
    const void* f1     = d_in[1];
    const void* f2     = d_in[2];
    const void* f3     = d_in[3];
    const void* f4     = d_in[4];
    const void* w3     = d_in[5];
    const void* bsh    = d_in[6];
    const void* wcls   = d_in[7];
    const void* bcls   = d_in[8];
    const void* wdelta = d_in[9];
    const void* bdelta = d_in[10];

    u16* W3p  = (u16*)d_ws;
    u16* W18p = W3p + W3P_ELEMS;
    int* flag = (int*)((char*)d_ws + FLAG_OFF_BYTES);

    detect_kernel<<<1, 64, 0, stream>>>((const u16*)f0, flag);
    repack_kernel<<<4672, 256, 0, stream>>>(w3, wcls, wdelta, W3p, W18p, flag);
    rpn_main<<<2728, 256, 0, stream>>>(f0, f1, f2, f3, f4,
                                       bsh, bcls, bdelta, W3p, W18p,
                                       d_out, flag);
}